// Round 1
// 572.158 us; speedup vs baseline: 1.0567x; 1.0567x over previous
//
#include <hip/hip_runtime.h>
#include <stdint.h>

// out = x @ (W + 2*L@R)^T + b.  x[8192,4096] fp32, W[4096,4096] fp32.
// Structure: prep (fused x->bf16 cvt + W_eff=W+2LR ->bf16) then 256^2 8-phase
// bf16 MFMA GEMM (m201 template: T1 XCD swizzle, T2 st_16x32 LDS swizzle,
// T3+T4 counted-vmcnt 8-phase pipeline, T5 setprio around MFMA clusters).
#define NTOK     8192
#define D_OUT    4096
#define D_IN     4096
#define LORA_DIM 16
#define LORA_SCALE 2.0f

typedef short  short8  __attribute__((ext_vector_type(8)));
typedef float  floatx4 __attribute__((ext_vector_type(4)));
typedef unsigned short ushort8 __attribute__((ext_vector_type(8)));

typedef unsigned int u32;
typedef __attribute__((address_space(3))) u32 lds_u32;
typedef __attribute__((address_space(1))) u32 glb_u32;

__device__ __forceinline__ unsigned short f2bf(float f) {
  unsigned int u = __builtin_bit_cast(unsigned int, f);
  u += 0x7FFFu + ((u >> 16) & 1u);
  return (unsigned short)(u >> 16);
}

__device__ __forceinline__ void copy16(const void* g, void* l) {
  __builtin_amdgcn_global_load_lds((glb_u32*)(uintptr_t)g, (lds_u32*)(uintptr_t)l,
                                   16, 0, 0);
}

// ---------------------------------------------------------------------------
// prep: fused  x fp32->bf16  AND  W_eff = W + 2*(L@R) -> bf16.
// Grid-stride in units of 8 elems; 2048 blocks * 256 thr = 524288 threads.
// Iters 0..7 cover exactly the x region (8*524288*8 = 8192*4096), iters
// 8..11 exactly the W region (4*524288*8 = 4096*4096) -> no divergence.
// ---------------------------------------------------------------------------
#define PTHREADS (2048 * 256)

__global__ __launch_bounds__(256) void prep(const float* __restrict__ X,
                                            const float* __restrict__ W,
                                            const float* __restrict__ L,
                                            const float* __restrict__ R,
                                            unsigned short* __restrict__ xb,
                                            unsigned short* __restrict__ wb) {
  const size_t t = (size_t)blockIdx.x * 256 + threadIdx.x;
#pragma unroll
  for (int it = 0; it < 8; ++it) {
    const size_t i = (t + (size_t)it * PTHREADS) * 8;
    const float4 a = *(const float4*)(X + i);
    const float4 b = *(const float4*)(X + i + 4);
    ushort8 o;
    o[0] = f2bf(a.x); o[1] = f2bf(a.y); o[2] = f2bf(a.z); o[3] = f2bf(a.w);
    o[4] = f2bf(b.x); o[5] = f2bf(b.y); o[6] = f2bf(b.z); o[7] = f2bf(b.w);
    *(ushort8*)(xb + i) = o;
  }
#pragma unroll
  for (int it = 0; it < 4; ++it) {
    const size_t v = t + (size_t)it * PTHREADS;   // W unit index
    const int o = (int)(v >> 9);                  // row (4096/8 = 512 units/row)
    const int ci = ((int)v & 511) * 8;            // col
    const float* wp = W + (size_t)o * D_IN + ci;
    const float4 a = *(const float4*)wp;
    const float4 b = *(const float4*)(wp + 4);
    float s0 = a.x, s1 = a.y, s2 = a.z, s3 = a.w;
    float s4 = b.x, s5 = b.y, s6 = b.z, s7 = b.w;
#pragma unroll
    for (int d = 0; d < LORA_DIM; ++d) {
      const float lc = LORA_SCALE * L[o * LORA_DIM + d];
      const float4 r0 = *(const float4*)(R + (size_t)d * D_IN + ci);
      const float4 r1 = *(const float4*)(R + (size_t)d * D_IN + ci + 4);
      s0 += lc * r0.x; s1 += lc * r0.y; s2 += lc * r0.z; s3 += lc * r0.w;
      s4 += lc * r1.x; s5 += lc * r1.y; s6 += lc * r1.z; s7 += lc * r1.w;
    }
    ushort8 ov;
    ov[0] = f2bf(s0); ov[1] = f2bf(s1); ov[2] = f2bf(s2); ov[3] = f2bf(s3);
    ov[4] = f2bf(s4); ov[5] = f2bf(s5); ov[6] = f2bf(s6); ov[7] = f2bf(s7);
    *(ushort8*)(wb + (size_t)o * D_IN + ci) = ov;
  }
}

// ---------------------------------------------------------------------------
// gemm8: C[M,N] = A[M,K]bf16 * B[N,K]bf16^T + bias, fp32 out.
// BM=BN=256, BK=64, 512 threads = 8 waves (2M x 4N), per-wave 128x64 out.
// LDS 128 KiB: 2 buffers x (A 32KB + B 32KB), tiles stored [256 rows][64 k]
// (128 B/row), halves = 128 rows (16KB = 512thr*16B*2 loads staging quantum).
// T2 swizzle: byte ^= ((byte>>9)&1)<<5, applied as inverse-permuted
// global_load_lds SOURCE (linear LDS dest) + swizzled ds_read address.
// Pipeline per K-tile T: ph1 stage (T+1).A0, ph2 (T+1).A1, ph4 (T+2).B0+B1;
// boundary s_waitcnt vmcnt(4) leaves exactly (T+2).B in flight.
// ---------------------------------------------------------------------------
#define BM 256
#define BN 256
#define BK 64

#define SWZ(d) ((d) ^ ((((d) >> 9) & 1) << 5))

#define BARRIER __builtin_amdgcn_s_barrier()
#define LGKM0 do { asm volatile("s_waitcnt lgkmcnt(0)" ::: "memory"); \
                   __builtin_amdgcn_sched_barrier(0); } while (0)

// stage one half-tile (H=0/1) of A (ABOFF=0) or B (ABOFF=32768) at k-tile KT
// into buffer byte offset BUFOFF. P = per-thread pre-swizzled row pointer.
#define STG(P, H, KT, BUFOFF, ABOFF) do {                                      \
    copy16((P) + (size_t)((H) * 128) * D_IN + (KT) * 64,                       \
           smem + (BUFOFF) + (ABOFF) + (H) * 16384 + tid * 16);                \
    copy16((P) + (size_t)((H) * 128 + 64) * D_IN + (KT) * 64,                  \
           smem + (BUFOFF) + (ABOFF) + (H) * 16384 + 8192 + tid * 16);         \
  } while (0)

#define LDA4(DST, MFB, KS, BUFOFF) do {                                        \
    DST[0] = *(const short8*)(smem + (BUFOFF) + SWZ((wm + ((MFB)+0)*16 + fr)*128 + (KS)*64 + fkb)); \
    DST[1] = *(const short8*)(smem + (BUFOFF) + SWZ((wm + ((MFB)+1)*16 + fr)*128 + (KS)*64 + fkb)); \
    DST[2] = *(const short8*)(smem + (BUFOFF) + SWZ((wm + ((MFB)+2)*16 + fr)*128 + (KS)*64 + fkb)); \
    DST[3] = *(const short8*)(smem + (BUFOFF) + SWZ((wm + ((MFB)+3)*16 + fr)*128 + (KS)*64 + fkb)); \
  } while (0)

#define LDB4(DST, KS, BUFOFF) do {                                             \
    DST[0] = *(const short8*)(smem + (BUFOFF) + 32768 + SWZ((wn + 0*16 + fr)*128 + (KS)*64 + fkb)); \
    DST[1] = *(const short8*)(smem + (BUFOFF) + 32768 + SWZ((wn + 1*16 + fr)*128 + (KS)*64 + fkb)); \
    DST[2] = *(const short8*)(smem + (BUFOFF) + 32768 + SWZ((wn + 2*16 + fr)*128 + (KS)*64 + fkb)); \
    DST[3] = *(const short8*)(smem + (BUFOFF) + 32768 + SWZ((wn + 3*16 + fr)*128 + (KS)*64 + fkb)); \
  } while (0)

#define MFMA16(MH4, BV) do {                                                   \
    _Pragma("unroll")                                                          \
    for (int i_ = 0; i_ < 4; ++i_) {                                           \
      _Pragma("unroll")                                                        \
      for (int j_ = 0; j_ < 4; ++j_)                                           \
        acc[(MH4) + i_][j_] = __builtin_amdgcn_mfma_f32_16x16x32_bf16(         \
            av[i_], (BV)[j_], acc[(MH4) + i_][j_], 0, 0, 0);                   \
    }                                                                          \
  } while (0)

// tile-boundary waits: counted vmcnt (never 0 mid-loop), hard fence both sides
#define ENDS4 do { asm volatile("s_waitcnt vmcnt(4)" ::: "memory");            \
    __builtin_amdgcn_sched_barrier(0); __builtin_amdgcn_s_barrier();           \
    asm volatile("" ::: "memory"); } while (0)
#define ENDS0 do { asm volatile("s_waitcnt vmcnt(0)" ::: "memory");            \
    __builtin_amdgcn_sched_barrier(0); __builtin_amdgcn_s_barrier();           \
    asm volatile("" ::: "memory"); } while (0)
#define ENDSN do { } while (0)

// one K-tile: 4 phases, each {ds_read subtile | stage | barrier | lgkm0 |
// setprio1 16xMFMA setprio0 | barrier}.  Quadrants: (kstep, M-half).
#define KTILE(BUF, OBUF, KT, SA, SB, ENDS) do {                                \
    short8 av[4], bv0[4], bv1[4];                                              \
    /* phase 1: ks=0, M-frags 0-3 */                                           \
    LDB4(bv0, 0, BUF);                                                         \
    LDA4(av, 0, 0, BUF);                                                       \
    if (SA) STG(pa, 0, (KT) + 1, OBUF, 0);                                     \
    BARRIER; LGKM0;                                                            \
    __builtin_amdgcn_s_setprio(1); MFMA16(0, bv0);                             \
    __builtin_amdgcn_s_setprio(0); BARRIER;                                    \
    /* phase 2: ks=0, M-frags 4-7 */                                           \
    LDA4(av, 4, 0, BUF);                                                       \
    if (SA) STG(pa, 1, (KT) + 1, OBUF, 0);                                     \
    BARRIER; LGKM0;                                                            \
    __builtin_amdgcn_s_setprio(1); MFMA16(4, bv0);                             \
    __builtin_amdgcn_s_setprio(0); BARRIER;                                    \
    /* phase 3: ks=1, M-frags 0-3 (no stage: B halves still hot) */            \
    LDB4(bv1, 1, BUF);                                                         \
    LDA4(av, 0, 1, BUF);                                                       \
    BARRIER; LGKM0;                                                            \
    __builtin_amdgcn_s_setprio(1); MFMA16(0, bv1);                             \
    __builtin_amdgcn_s_setprio(0); BARRIER;                                    \
    /* phase 4: ks=1, M-frags 4-7; stage (T+2).B into the live buffer */       \
    LDA4(av, 4, 1, BUF);                                                       \
    if (SB) { STG(pb, 0, (KT) + 2, BUF, 32768);                                \
              STG(pb, 1, (KT) + 2, BUF, 32768); }                              \
    BARRIER; LGKM0;                                                            \
    __builtin_amdgcn_s_setprio(1); MFMA16(4, bv1);                             \
    __builtin_amdgcn_s_setprio(0);                                             \
    ENDS;                                                                      \
  } while (0)

__global__ __launch_bounds__(512, 2) void gemm8(
    const unsigned short* __restrict__ A,   // [NTOK, D_IN] bf16
    const unsigned short* __restrict__ B,   // [D_OUT, D_IN] bf16 (W_eff)
    const float* __restrict__ bias,
    float* __restrict__ C) {                // [NTOK, D_OUT] fp32
  __shared__ __align__(16) unsigned char smem[131072];

  const int tid = threadIdx.x;
  const int lane = tid & 63;
  const int w  = tid >> 6;
  const int wm = (w >> 2) * 128;            // wave M origin in tile
  const int wn = (w & 3) * 64;              // wave N origin in tile
  const int fr  = lane & 15;
  const int fkb = (lane >> 4) * 16;         // frag k byte offset

  // T1: bijective XCD swizzle (512 WGs, 512%8==0): chunk of 64 per XCD,
  // n-major -> each XCD keeps 2 B-panels (4MB) L2-resident.
  const int bid  = blockIdx.x;
  const int swzb = (bid & 7) * 64 + (bid >> 3);
  const int m0 = (swzb & 31) * BM;
  const int n0 = (swzb >> 5) * BN;

  // T2 staging: linear LDS dest (tid*16), inverse-swizzled global source.
  // dest D = l*8192 + tid*16; src elem off = SWZ(D) -> t_src = tid ^ bit5<<1.
  const int tsrc = tid ^ (((tid >> 5) & 1) << 1);
  const int sr_  = tsrc >> 3;               // source row 0..63 (per load l +64)
  const int sc8  = (tsrc & 7) * 8;          // source col (bf16 elems)
  const unsigned short* pa = A + (size_t)(m0 + sr_) * D_IN + sc8;
  const unsigned short* pb = B + (size_t)(n0 + sr_) * D_IN + sc8;

  floatx4 acc[8][4] = {};

  // prologue: T0 fully (8 loads) + T1.B (4 loads); vmcnt(4) => T0 landed.
  STG(pa, 0, 0, 0, 0);       STG(pa, 1, 0, 0, 0);
  STG(pb, 0, 0, 0, 32768);   STG(pb, 1, 0, 0, 32768);
  STG(pb, 0, 1, 65536, 32768); STG(pb, 1, 1, 65536, 32768);
  ENDS4;

  // main loop: tiles 0..61 (31 x 2), then peeled 62 (drain) and 63 (no stage)
  for (int t2 = 0; t2 < 31; ++t2) {
    const int T = t2 * 2;
    KTILE(0,     65536, T,     true, true, ENDS4);
    KTILE(65536, 0,     T + 1, true, true, ENDS4);
  }
  KTILE(0,     65536, 62, true,  false, ENDS0);
  KTILE(65536, 0,     63, false, false, ENDSN);

  // epilogue: C/D layout col=lane&15, row=(lane>>4)*4+reg (m89/m91-verified)
  const int q4 = (lane >> 4) * 4;
#pragma unroll
  for (int j = 0; j < 4; ++j) {
    const int col = n0 + wn + j * 16 + fr;
    const float bs = bias[col];
#pragma unroll
    for (int i = 0; i < 8; ++i) {
      const size_t row = (size_t)(m0 + wm + i * 16 + q4);
      const floatx4 v = acc[i][j];
#pragma unroll
      for (int r = 0; r < 4; ++r)
        C[(row + r) * D_OUT + col] = v[r] + bs;
    }
  }
}

// ---------------------------------------------------------------------------
extern "C" void kernel_launch(void* const* d_in, const int* in_sizes, int n_in,
                              void* d_out, int out_size, void* d_ws, size_t ws_size,
                              hipStream_t stream) {
  const float* x    = (const float*)d_in[0];
  const float* W    = (const float*)d_in[1];
  const float* bias = (const float*)d_in[2];
  const float* L    = (const float*)d_in[3];
  const float* R    = (const float*)d_in[4];
  float* out = (float*)d_out;

  const size_t need = ((size_t)NTOK * D_IN + (size_t)D_OUT * D_IN) * sizeof(unsigned short);
  if (ws_size < need) return;

  unsigned short* xb = (unsigned short*)d_ws;
  unsigned short* wb = xb + (size_t)NTOK * D_IN;

  prep<<<2048, 256, 0, stream>>>(x, W, L, R, xb, wb);
  gemm8<<<dim3((NTOK / BM) * (D_OUT / BN)), 512, 0, stream>>>(xb, wb, bias, out);
}

// Round 2
// 558.388 us; speedup vs baseline: 1.0828x; 1.0247x over previous
//
#include <hip/hip_runtime.h>
#include <stdint.h>

// out = x @ (W + 2*L@R)^T + b,  x[8192,4096] fp32, W[4096,4096] fp32.
// Decomposition (removes the L@R prep GEMM entirely):
//   out = x@W^T + (2*(x@R^T))@L^T + b
//   cvt:     x->bf16, W->bf16 (pure cast), R->bf16, Lb = [L | 0] bf16 [4096,32]
//   lora_xr: y1b = [2*(x@R^T) | 0] bf16 [8192,32]  (tiny MFMA GEMM, K=4096)
//   gemm8:   256^2 8-phase bf16 MFMA GEMM over K=4096, then ONE peeled K=32
//            MFMA step with (y1b, Lb) adds the rank-16 LoRA term.
#define NTOK     8192
#define D_OUT    4096
#define D_IN     4096
#define LORA_DIM 16

typedef short  short8  __attribute__((ext_vector_type(8)));
typedef float  floatx4 __attribute__((ext_vector_type(4)));
typedef unsigned short ushort8 __attribute__((ext_vector_type(8)));

typedef unsigned int u32;
typedef __attribute__((address_space(3))) u32 lds_u32;
typedef __attribute__((address_space(1))) u32 glb_u32;

__device__ __forceinline__ unsigned short f2bf(float f) {
  unsigned int u = __builtin_bit_cast(unsigned int, f);
  u += 0x7FFFu + ((u >> 16) & 1u);
  return (unsigned short)(u >> 16);
}

__device__ __forceinline__ void copy16(const void* g, void* l) {
  __builtin_amdgcn_global_load_lds((glb_u32*)(uintptr_t)g, (lds_u32*)(uintptr_t)l,
                                   16, 0, 0);
}

__device__ __forceinline__ void cvt8(const float* __restrict__ s,
                                     unsigned short* __restrict__ d) {
  const float4 a = *(const float4*)s;
  const float4 b = *(const float4*)(s + 4);
  ushort8 o;
  o[0] = f2bf(a.x); o[1] = f2bf(a.y); o[2] = f2bf(a.z); o[3] = f2bf(a.w);
  o[4] = f2bf(b.x); o[5] = f2bf(b.y); o[6] = f2bf(b.z); o[7] = f2bf(b.w);
  *(ushort8*)d = o;
}

// ---------------------------------------------------------------------------
// cvt: pure-cast streaming. x (8 iters) + W (4 iters) exactly tile the
// regions; small tails cast R and build Lb = [L | zeros].
// ---------------------------------------------------------------------------
#define PTHREADS (2048 * 256)

__global__ __launch_bounds__(256) void cvt(const float* __restrict__ X,
                                           const float* __restrict__ W,
                                           const float* __restrict__ L,
                                           const float* __restrict__ R,
                                           unsigned short* __restrict__ xb,
                                           unsigned short* __restrict__ wb,
                                           unsigned short* __restrict__ Rb,
                                           unsigned short* __restrict__ Lb) {
  const size_t t = (size_t)blockIdx.x * 256 + threadIdx.x;
#pragma unroll
  for (int it = 0; it < 8; ++it) {
    const size_t i = (t + (size_t)it * PTHREADS) * 8;
    cvt8(X + i, xb + i);
  }
#pragma unroll
  for (int it = 0; it < 4; ++it) {
    const size_t i = (t + (size_t)it * PTHREADS) * 8;
    cvt8(W + i, wb + i);
  }
  if (t < (LORA_DIM * D_IN) / 8) cvt8(R + t * 8, Rb + t * 8);
  if (t < D_OUT) {
    const float4 l0 = *(const float4*)(L + t * 16);
    const float4 l1 = *(const float4*)(L + t * 16 + 4);
    const float4 l2 = *(const float4*)(L + t * 16 + 8);
    const float4 l3 = *(const float4*)(L + t * 16 + 12);
    ushort8 o0, o1;
    o0[0] = f2bf(l0.x); o0[1] = f2bf(l0.y); o0[2] = f2bf(l0.z); o0[3] = f2bf(l0.w);
    o0[4] = f2bf(l1.x); o0[5] = f2bf(l1.y); o0[6] = f2bf(l1.z); o0[7] = f2bf(l1.w);
    o1[0] = f2bf(l2.x); o1[1] = f2bf(l2.y); o1[2] = f2bf(l2.z); o1[3] = f2bf(l2.w);
    o1[4] = f2bf(l3.x); o1[5] = f2bf(l3.y); o1[6] = f2bf(l3.z); o1[7] = f2bf(l3.w);
    *(ushort8*)(Lb + t * 32) = o0;
    *(ushort8*)(Lb + t * 32 + 8) = o1;
    const float4 z = make_float4(0.f, 0.f, 0.f, 0.f);
    *(float4*)(Lb + t * 32 + 16) = z;   // bf16 cols 16..23 = 0
    *(float4*)(Lb + t * 32 + 24) = z;   // bf16 cols 24..31 = 0
  }
}

// ---------------------------------------------------------------------------
// lora_xr: y1b[8192][32] = [ 2*(x@R^T) | zeros ] in bf16.
// One wave per 16 rows of x (512 waves, 128 blocks); MFMA 16x16x32,
// N = LORA_DIM = 16; A frags loaded straight from xb, B from Rb (L2-hot).
// ---------------------------------------------------------------------------
__global__ __launch_bounds__(256) void lora_xr(const unsigned short* __restrict__ xb,
                                               const unsigned short* __restrict__ Rb,
                                               unsigned short* __restrict__ y1b) {
  const int wid = (int)((blockIdx.x * 256 + threadIdx.x) >> 6);   // 0..511
  const int lane = threadIdx.x & 63;
  const int mb = wid * 16;
  const int fr = lane & 15;
  const int fke = (lane >> 4) * 8;              // frag k offset (elems)
  floatx4 acc = {0.f, 0.f, 0.f, 0.f};
  const unsigned short* ap = xb + (size_t)(mb + fr) * D_IN + fke;
  const unsigned short* bp = Rb + (size_t)fr * D_IN + fke;
#pragma unroll 8
  for (int k0 = 0; k0 < D_IN; k0 += 32) {
    const short8 av = *(const short8*)(ap + k0);
    const short8 bv = *(const short8*)(bp + k0);
    acc = __builtin_amdgcn_mfma_f32_16x16x32_bf16(av, bv, acc, 0, 0, 0);
  }
  // C/D layout: col = lane&15 (= d), row = (lane>>4)*4 + r
  const int q = (lane >> 4) * 4;
#pragma unroll
  for (int r = 0; r < 4; ++r)
    y1b[(size_t)(mb + q + r) * 32 + fr] = f2bf(2.0f * acc[r]);
  if (lane < 16) {                              // zero-pad cols 16..31
    const float4 z = make_float4(0.f, 0.f, 0.f, 0.f);
    *(float4*)(y1b + (size_t)(mb + lane) * 32 + 16) = z;
    *(float4*)(y1b + (size_t)(mb + lane) * 32 + 24) = z;
  }
}

// ---------------------------------------------------------------------------
// gemm8: C = A[M,K]bf16 * B[N,K]bf16^T (+ rank-16 LoRA step) + bias.
// BM=BN=256, BK=64, 8 waves (2Mx4N). LDS 128 KiB, 2 buffers x (A 32K + B 32K),
// tiles [256 rows][64 k] = 128 B/row.
// T2 swizzle (FIXED vs R1): physical = logical ^ ((row&7)<<4). A b128 frag
// read (lanes 0-15 same k-slot, rows r..r+15) now covers all 8 16-B slots of
// a row (2-way alias = free, m136), vs R1's 1-bit XOR that left 8-way.
// Staging keeps linear LDS dest (rule #21): source thread perm
// tsrc = tid ^ ((tid>>3)&7)  (row = tid>>3  => same involution, coalesced).
// ---------------------------------------------------------------------------
#define BM 256
#define BN 256
#define BK 64

#define SWZ(d) ((d) ^ ((((d) >> 7) & 7) << 4))

#define BARRIER __builtin_amdgcn_s_barrier()
#define LGKM0 do { asm volatile("s_waitcnt lgkmcnt(0)" ::: "memory"); \
                   __builtin_amdgcn_sched_barrier(0); } while (0)

#define STG(P, H, KT, BUFOFF, ABOFF) do {                                      \
    copy16((P) + (size_t)((H) * 128) * D_IN + (KT) * 64,                       \
           smem + (BUFOFF) + (ABOFF) + (H) * 16384 + tid * 16);                \
    copy16((P) + (size_t)((H) * 128 + 64) * D_IN + (KT) * 64,                  \
           smem + (BUFOFF) + (ABOFF) + (H) * 16384 + 8192 + tid * 16);         \
  } while (0)

#define LDA4(DST, MFB, KS, BUFOFF) do {                                        \
    DST[0] = *(const short8*)(smem + (BUFOFF) + SWZ((wm + ((MFB)+0)*16 + fr)*128 + (KS)*64 + fkb)); \
    DST[1] = *(const short8*)(smem + (BUFOFF) + SWZ((wm + ((MFB)+1)*16 + fr)*128 + (KS)*64 + fkb)); \
    DST[2] = *(const short8*)(smem + (BUFOFF) + SWZ((wm + ((MFB)+2)*16 + fr)*128 + (KS)*64 + fkb)); \
    DST[3] = *(const short8*)(smem + (BUFOFF) + SWZ((wm + ((MFB)+3)*16 + fr)*128 + (KS)*64 + fkb)); \
  } while (0)

#define LDB4(DST, KS, BUFOFF) do {                                             \
    DST[0] = *(const short8*)(smem + (BUFOFF) + 32768 + SWZ((wn + 0*16 + fr)*128 + (KS)*64 + fkb)); \
    DST[1] = *(const short8*)(smem + (BUFOFF) + 32768 + SWZ((wn + 1*16 + fr)*128 + (KS)*64 + fkb)); \
    DST[2] = *(const short8*)(smem + (BUFOFF) + 32768 + SWZ((wn + 2*16 + fr)*128 + (KS)*64 + fkb)); \
    DST[3] = *(const short8*)(smem + (BUFOFF) + 32768 + SWZ((wn + 3*16 + fr)*128 + (KS)*64 + fkb)); \
  } while (0)

#define MFMA16(MH4, BV) do {                                                   \
    _Pragma("unroll")                                                          \
    for (int i_ = 0; i_ < 4; ++i_) {                                           \
      _Pragma("unroll")                                                        \
      for (int j_ = 0; j_ < 4; ++j_)                                           \
        acc[(MH4) + i_][j_] = __builtin_amdgcn_mfma_f32_16x16x32_bf16(         \
            av[i_], (BV)[j_], acc[(MH4) + i_][j_], 0, 0, 0);                   \
    }                                                                          \
  } while (0)

#define ENDS4 do { asm volatile("s_waitcnt vmcnt(4)" ::: "memory");            \
    __builtin_amdgcn_sched_barrier(0); __builtin_amdgcn_s_barrier();           \
    asm volatile("" ::: "memory"); } while (0)
#define ENDS0 do { asm volatile("s_waitcnt vmcnt(0)" ::: "memory");            \
    __builtin_amdgcn_sched_barrier(0); __builtin_amdgcn_s_barrier();           \
    asm volatile("" ::: "memory"); } while (0)
#define ENDSN do { } while (0)

#define KTILE(BUF, OBUF, KT, SA, SB, ENDS) do {                                \
    short8 av[4], bv0[4], bv1[4];                                              \
    /* phase 1: ks=0, M-frags 0-3; stage (T+1).A0 */                           \
    LDB4(bv0, 0, BUF);                                                         \
    LDA4(av, 0, 0, BUF);                                                       \
    if (SA) STG(pa, 0, (KT) + 1, OBUF, 0);                                     \
    BARRIER; LGKM0;                                                            \
    __builtin_amdgcn_s_setprio(1); MFMA16(0, bv0);                             \
    __builtin_amdgcn_s_setprio(0); BARRIER;                                    \
    /* phase 2: ks=0, M-frags 4-7; stage (T+1).A1 */                           \
    LDA4(av, 4, 0, BUF);                                                       \
    if (SA) STG(pa, 1, (KT) + 1, OBUF, 0);                                     \
    BARRIER; LGKM0;                                                            \
    __builtin_amdgcn_s_setprio(1); MFMA16(4, bv0);                             \
    __builtin_amdgcn_s_setprio(0); BARRIER;                                    \
    /* phase 3: ks=1, M-frags 0-3 (no stage: B halves still hot) */            \
    LDB4(bv1, 1, BUF);                                                         \
    LDA4(av, 0, 1, BUF);                                                       \
    BARRIER; LGKM0;                                                            \
    __builtin_amdgcn_s_setprio(1); MFMA16(0, bv1);                             \
    __builtin_amdgcn_s_setprio(0); BARRIER;                                    \
    /* phase 4: ks=1, M-frags 4-7; stage (T+2).B into live buffer */           \
    LDA4(av, 4, 1, BUF);                                                       \
    if (SB) { STG(pb, 0, (KT) + 2, BUF, 32768);                                \
              STG(pb, 1, (KT) + 2, BUF, 32768); }                              \
    BARRIER; LGKM0;                                                            \
    __builtin_amdgcn_s_setprio(1); MFMA16(4, bv1);                             \
    __builtin_amdgcn_s_setprio(0);                                             \
    ENDS;                                                                      \
  } while (0)

__global__ __launch_bounds__(512, 2) void gemm8(
    const unsigned short* __restrict__ A,    // [NTOK, D_IN] bf16
    const unsigned short* __restrict__ B,    // [D_OUT, D_IN] bf16 (W cast)
    const float* __restrict__ bias,
    const unsigned short* __restrict__ y1b,  // [NTOK, 32] bf16 (cols 16-31 = 0)
    const unsigned short* __restrict__ Lb,   // [D_OUT, 32] bf16 (cols 16-31 = 0)
    float* __restrict__ C) {                 // [NTOK, D_OUT] fp32
  __shared__ __align__(16) unsigned char smem[131072];

  const int tid = threadIdx.x;
  const int lane = tid & 63;
  const int w  = tid >> 6;
  const int wm = (w >> 2) * 128;
  const int wn = (w & 3) * 64;
  const int fr  = lane & 15;
  const int fkb = (lane >> 4) * 16;          // frag k byte offset
  const int fke = (lane >> 4) * 8;           // frag k elem offset

  // T1: bijective XCD swizzle (512 WGs, 512%8==0)
  const int bid  = blockIdx.x;
  const int swzb = (bid & 7) * 64 + (bid >> 3);
  const int m0 = (swzb & 31) * BM;
  const int n0 = (swzb >> 5) * BN;

  // T2 staging: linear LDS dest, source permuted by the same involution.
  const int tsrc = tid ^ ((tid >> 3) & 7);
  const int sr_  = tsrc >> 3;                // = tid>>3 (row unchanged)
  const int sc8  = (tsrc & 7) * 8;           // permuted 16-B slot in row
  const unsigned short* pa = A + (size_t)(m0 + sr_) * D_IN + sc8;
  const unsigned short* pb = B + (size_t)(n0 + sr_) * D_IN + sc8;

  floatx4 acc[8][4] = {};

  // prologue: T0 fully (8 loads) + T1.B (4 loads); vmcnt(4) => T0 landed.
  STG(pa, 0, 0, 0, 0);       STG(pa, 1, 0, 0, 0);
  STG(pb, 0, 0, 0, 32768);   STG(pb, 1, 0, 0, 32768);
  STG(pb, 0, 1, 65536, 32768); STG(pb, 1, 1, 65536, 32768);
  ENDS4;

  for (int t2 = 0; t2 < 31; ++t2) {
    const int T = t2 * 2;
    KTILE(0,     65536, T,     true, true, ENDS4);
    KTILE(65536, 0,     T + 1, true, true, ENDS4);
  }
  KTILE(0,     65536, 62, true,  false, ENDS0);
  KTILE(65536, 0,     63, false, false, ENDSN);

  // peeled rank-16 LoRA K-step: one K=32 MFMA pass from y1b/Lb (L2-hot,
  // 64-B rows; zero-padded cols make the upper half of K a no-op).
  {
    short8 lbv[4];
#pragma unroll
    for (int j = 0; j < 4; ++j)
      lbv[j] = *(const short8*)(Lb + (size_t)(n0 + wn + j * 16 + fr) * 32 + fke);
#pragma unroll
    for (int i = 0; i < 8; ++i) {
      const short8 yav = *(const short8*)(y1b + (size_t)(m0 + wm + i * 16 + fr) * 32 + fke);
#pragma unroll
      for (int j = 0; j < 4; ++j)
        acc[i][j] = __builtin_amdgcn_mfma_f32_16x16x32_bf16(yav, lbv[j],
                                                            acc[i][j], 0, 0, 0);
    }
  }

  // epilogue: C/D layout col=lane&15, row=(lane>>4)*4+reg
  const int q4 = (lane >> 4) * 4;
#pragma unroll
  for (int j = 0; j < 4; ++j) {
    const int col = n0 + wn + j * 16 + fr;
    const float bs = bias[col];
#pragma unroll
    for (int i = 0; i < 8; ++i) {
      const size_t row = (size_t)(m0 + wm + i * 16 + q4);
      const floatx4 v = acc[i][j];
#pragma unroll
      for (int r = 0; r < 4; ++r)
        C[(row + r) * D_OUT + col] = v[r] + bs;
    }
  }
}

// ---------------------------------------------------------------------------
extern "C" void kernel_launch(void* const* d_in, const int* in_sizes, int n_in,
                              void* d_out, int out_size, void* d_ws, size_t ws_size,
                              hipStream_t stream) {
  const float* x    = (const float*)d_in[0];
  const float* W    = (const float*)d_in[1];
  const float* bias = (const float*)d_in[2];
  const float* L    = (const float*)d_in[3];
  const float* R    = (const float*)d_in[4];
  float* out = (float*)d_out;

  // ws: xb 64M | wb 32M | y1b 512K | Rb 128K | Lb 256K  (bf16)
  const size_t n_xb  = (size_t)NTOK * D_IN;
  const size_t n_wb  = (size_t)D_OUT * D_IN;
  const size_t n_y1b = (size_t)NTOK * 32;
  const size_t n_rb  = (size_t)LORA_DIM * D_IN;
  const size_t n_lb  = (size_t)D_OUT * 32;
  const size_t need = (n_xb + n_wb + n_y1b + n_rb + n_lb) * sizeof(unsigned short);
  if (ws_size < need) return;

  unsigned short* xb  = (unsigned short*)d_ws;
  unsigned short* wb  = xb + n_xb;
  unsigned short* y1b = wb + n_wb;
  unsigned short* Rb  = y1b + n_y1b;
  unsigned short* Lb  = Rb + n_rb;

  cvt<<<2048, 256, 0, stream>>>(x, W, L, R, xb, wb, Rb, Lb);
  lora_xr<<<128, 256, 0, stream>>>(xb, Rb, y1b);
  gemm8<<<dim3((NTOK / BM) * (D_OUT / BN)), 512, 0, stream>>>(xb, wb, bias, y1b, Lb, out);
}

// Round 3
// 547.676 us; speedup vs baseline: 1.1040x; 1.0196x over previous
//
#include <hip/hip_runtime.h>
#include <stdint.h>

// out = x @ (W + 2*L@R)^T + b,  x[8192,4096] fp32, W[4096,4096] fp32.
//   out = x@W^T + (2*(x@R^T))@L^T + b
//   cvt:     x->bf16, W->bf16 (pure cast), R->bf16, Lb = [L | 0] bf16
//   lora_xr: y1b = [2*(x@R^T) | 0] bf16 [8192,32]  (512 blocks, K-split waves)
//   gemm8:   256^2 bf16 MFMA GEMM, 2-barrier/K-tile pipelined schedule,
//            + one peeled K=32 MFMA step for the rank-16 LoRA term.
#define NTOK     8192
#define D_OUT    4096
#define D_IN     4096
#define LORA_DIM 16

typedef short  short8  __attribute__((ext_vector_type(8)));
typedef float  floatx4 __attribute__((ext_vector_type(4)));
typedef unsigned short ushort8 __attribute__((ext_vector_type(8)));

typedef unsigned int u32;
typedef __attribute__((address_space(3))) u32 lds_u32;
typedef __attribute__((address_space(1))) u32 glb_u32;

__device__ __forceinline__ unsigned short f2bf(float f) {
  unsigned int u = __builtin_bit_cast(unsigned int, f);
  u += 0x7FFFu + ((u >> 16) & 1u);
  return (unsigned short)(u >> 16);
}

__device__ __forceinline__ void copy16(const void* g, void* l) {
  __builtin_amdgcn_global_load_lds((glb_u32*)(uintptr_t)g, (lds_u32*)(uintptr_t)l,
                                   16, 0, 0);
}

__device__ __forceinline__ void cvt8(const float* __restrict__ s,
                                     unsigned short* __restrict__ d) {
  const float4 a = *(const float4*)s;
  const float4 b = *(const float4*)(s + 4);
  ushort8 o;
  o[0] = f2bf(a.x); o[1] = f2bf(a.y); o[2] = f2bf(a.z); o[3] = f2bf(a.w);
  o[4] = f2bf(b.x); o[5] = f2bf(b.y); o[6] = f2bf(b.z); o[7] = f2bf(b.w);
  *(ushort8*)d = o;
}

// ---------------------------------------------------------------------------
// cvt: pure-cast streaming. x (8 iters) + W (4 iters) exactly tile the
// regions; small tails cast R and build Lb = [L | zeros].
// ---------------------------------------------------------------------------
#define PTHREADS (2048 * 256)

__global__ __launch_bounds__(256) void cvt(const float* __restrict__ X,
                                           const float* __restrict__ W,
                                           const float* __restrict__ L,
                                           const float* __restrict__ R,
                                           unsigned short* __restrict__ xb,
                                           unsigned short* __restrict__ wb,
                                           unsigned short* __restrict__ Rb,
                                           unsigned short* __restrict__ Lb) {
  const size_t t = (size_t)blockIdx.x * 256 + threadIdx.x;
#pragma unroll
  for (int it = 0; it < 8; ++it) {
    const size_t i = (t + (size_t)it * PTHREADS) * 8;
    cvt8(X + i, xb + i);
  }
#pragma unroll
  for (int it = 0; it < 4; ++it) {
    const size_t i = (t + (size_t)it * PTHREADS) * 8;
    cvt8(W + i, wb + i);
  }
  if (t < (LORA_DIM * D_IN) / 8) cvt8(R + t * 8, Rb + t * 8);
  if (t < D_OUT) {
    const float4 l0 = *(const float4*)(L + t * 16);
    const float4 l1 = *(const float4*)(L + t * 16 + 4);
    const float4 l2 = *(const float4*)(L + t * 16 + 8);
    const float4 l3 = *(const float4*)(L + t * 16 + 12);
    ushort8 o0, o1;
    o0[0] = f2bf(l0.x); o0[1] = f2bf(l0.y); o0[2] = f2bf(l0.z); o0[3] = f2bf(l0.w);
    o0[4] = f2bf(l1.x); o0[5] = f2bf(l1.y); o0[6] = f2bf(l1.z); o0[7] = f2bf(l1.w);
    o1[0] = f2bf(l2.x); o1[1] = f2bf(l2.y); o1[2] = f2bf(l2.z); o1[3] = f2bf(l2.w);
    o1[4] = f2bf(l3.x); o1[5] = f2bf(l3.y); o1[6] = f2bf(l3.z); o1[7] = f2bf(l3.w);
    *(ushort8*)(Lb + t * 32) = o0;
    *(ushort8*)(Lb + t * 32 + 8) = o1;
    const float4 z = make_float4(0.f, 0.f, 0.f, 0.f);
    *(float4*)(Lb + t * 32 + 16) = z;
    *(float4*)(Lb + t * 32 + 24) = z;
  }
}

// ---------------------------------------------------------------------------
// lora_xr v2: y1b[8192][32] = [ 2*(x@R^T) | zeros ] bf16.
// 512 blocks x 4 waves; block handles 16 rows; waves split K 4-way (32
// MFMA iters each, vs 128-deep serial chain at 0.5 wave/SIMD before);
// LDS tree-reduce, wave 0 writes.
// ---------------------------------------------------------------------------
__global__ __launch_bounds__(256) void lora_xr(const unsigned short* __restrict__ xb,
                                               const unsigned short* __restrict__ Rb,
                                               unsigned short* __restrict__ y1b) {
  __shared__ float red[4][256];
  const int tid = threadIdx.x;
  const int wv = tid >> 6;
  const int lane = tid & 63;
  const int mb = blockIdx.x * 16;
  const int fr = lane & 15;
  const int fke = (lane >> 4) * 8;
  const int kw = wv * 1024;
  floatx4 acc = {0.f, 0.f, 0.f, 0.f};
  const unsigned short* ap = xb + (size_t)(mb + fr) * D_IN + kw + fke;
  const unsigned short* bp = Rb + (size_t)fr * D_IN + kw + fke;
#pragma unroll 8
  for (int k = 0; k < 1024; k += 32) {
    const short8 av = *(const short8*)(ap + k);
    const short8 bv = *(const short8*)(bp + k);
    acc = __builtin_amdgcn_mfma_f32_16x16x32_bf16(av, bv, acc, 0, 0, 0);
  }
  *(floatx4*)&red[wv][lane * 4] = acc;
  __syncthreads();
  if (wv == 0) {
    floatx4 s = *(const floatx4*)&red[0][lane * 4];
    s += *(const floatx4*)&red[1][lane * 4];
    s += *(const floatx4*)&red[2][lane * 4];
    s += *(const floatx4*)&red[3][lane * 4];
    const int q = (lane >> 4) * 4;
#pragma unroll
    for (int r = 0; r < 4; ++r)
      y1b[(size_t)(mb + q + r) * 32 + fr] = f2bf(2.0f * s[r]);
    if (lane < 16) {
      const float4 z = make_float4(0.f, 0.f, 0.f, 0.f);
      *(float4*)(y1b + (size_t)(mb + lane) * 32 + 16) = z;
      *(float4*)(y1b + (size_t)(mb + lane) * 32 + 24) = z;
    }
  }
}

// ---------------------------------------------------------------------------
// gemm8 v3: C = A[M,K]bf16 * B[N,K]bf16^T (+ LoRA peel) + bias.
// BM=BN=256, BK=64, 8 waves (2Mx4N). LDS 128 KiB double-buffered.
// v3 change: 2 barriers per K-tile (was 9). The per-phase barriers
// serialized LDS-drain and MFMA epochs (measured: 240us ~= 110 MFMA +
// 123 LDS, zero overlap). Reads are issued one group ahead of the
// consuming MFMA cluster; compiler inserts correct counted lgkmcnt waits
// (dependency-driven). Raw s_barrier (no auto-drain). Hazards kept:
//  - mid barrier: all waves' B-reads complete (operand deps) before
//    staging B(T+2) into the live buffer.
//  - boundary vmcnt(4)+barrier: [B(T+1):4][A(T+1):4][B(T+2):4] -> wait 4
//    leaves only B(T+2) in flight; next tile's buffer fully landed.
// T2 swizzle hoisted: addr = rowbase + frag*2048 + kx[ks], where
// kx = (ks*64 + fkb) ^ ((fr&7)<<4)  (XOR bits 4-6 disjoint from adds).
// ---------------------------------------------------------------------------
#define BM 256
#define BN 256
#define BK 64

#define SETP1 __builtin_amdgcn_s_setprio(1)
#define SETP0 __builtin_amdgcn_s_setprio(0)

#define STG(P, H, KT, BUFOFF, ABOFF) do {                                      \
    copy16((P) + (size_t)((H) * 128) * D_IN + (KT) * 64,                       \
           smem + (BUFOFF) + (ABOFF) + (H) * 16384 + tid * 16);                \
    copy16((P) + (size_t)((H) * 128 + 64) * D_IN + (KT) * 64,                  \
           smem + (BUFOFF) + (ABOFF) + (H) * 16384 + 8192 + tid * 16);         \
  } while (0)

#define LDA4(DST, MFB, KX, BUFOFF) do {                                        \
    DST[0] = *(const short8*)(smem + (BUFOFF) + baseA + ((MFB)+0)*2048 + (KX)); \
    DST[1] = *(const short8*)(smem + (BUFOFF) + baseA + ((MFB)+1)*2048 + (KX)); \
    DST[2] = *(const short8*)(smem + (BUFOFF) + baseA + ((MFB)+2)*2048 + (KX)); \
    DST[3] = *(const short8*)(smem + (BUFOFF) + baseA + ((MFB)+3)*2048 + (KX)); \
  } while (0)

#define LDB4(DST, KX, BUFOFF) do {                                             \
    DST[0] = *(const short8*)(smem + (BUFOFF) + baseB + 0*2048 + (KX));        \
    DST[1] = *(const short8*)(smem + (BUFOFF) + baseB + 1*2048 + (KX));        \
    DST[2] = *(const short8*)(smem + (BUFOFF) + baseB + 2*2048 + (KX));        \
    DST[3] = *(const short8*)(smem + (BUFOFF) + baseB + 3*2048 + (KX));        \
  } while (0)

#define MFMA16(MH4, AV, BV) do {                                               \
    _Pragma("unroll")                                                          \
    for (int i_ = 0; i_ < 4; ++i_) {                                           \
      _Pragma("unroll")                                                        \
      for (int j_ = 0; j_ < 4; ++j_)                                           \
        acc[(MH4) + i_][j_] = __builtin_amdgcn_mfma_f32_16x16x32_bf16(         \
            (AV)[i_], (BV)[j_], acc[(MH4) + i_][j_], 0, 0, 0);                 \
    }                                                                          \
  } while (0)

#define MIDBAR do { __builtin_amdgcn_sched_barrier(0);                         \
    __builtin_amdgcn_s_barrier(); __builtin_amdgcn_sched_barrier(0); } while (0)

#define ENDS4 do { asm volatile("s_waitcnt vmcnt(4)" ::: "memory");            \
    __builtin_amdgcn_sched_barrier(0); __builtin_amdgcn_s_barrier();           \
    asm volatile("" ::: "memory"); } while (0)
#define ENDS0 do { asm volatile("s_waitcnt vmcnt(0)" ::: "memory");            \
    __builtin_amdgcn_sched_barrier(0); __builtin_amdgcn_s_barrier();           \
    asm volatile("" ::: "memory"); } while (0)
#define ENDSN do { } while (0)

// One K-tile, 2 barriers. Read groups issued one cluster ahead:
//   Ra(8) Rb(4) | MFMA_a | Rc(8) | MFMA_b | Rd(4) | MFMA_c | MID |
//   STG B(T+2) | MFMA_d | ENDS
#define KTILE(BUF, OBUF, KT, SA, SB, ENDS) do {                                \
    short8 av0[4], av1[4], av2[4], av3[4], bv0[4], bv1[4];                     \
    if (SA) { STG(pa, 0, (KT) + 1, OBUF, 0);                                   \
              STG(pa, 1, (KT) + 1, OBUF, 0); }                                 \
    LDB4(bv0, kx0, BUF);                                                       \
    LDA4(av0, 0, kx0, BUF);                                                    \
    LDA4(av1, 4, kx0, BUF);                                                    \
    SETP1; MFMA16(0, av0, bv0); SETP0;                                         \
    LDB4(bv1, kx1, BUF);                                                       \
    LDA4(av2, 0, kx1, BUF);                                                    \
    SETP1; MFMA16(4, av1, bv0); SETP0;                                         \
    LDA4(av3, 4, kx1, BUF);                                                    \
    SETP1; MFMA16(0, av2, bv1); SETP0;                                         \
    MIDBAR;                                                                    \
    if (SB) { STG(pb, 0, (KT) + 2, BUF, 32768);                                \
              STG(pb, 1, (KT) + 2, BUF, 32768); }                              \
    SETP1; MFMA16(4, av3, bv1); SETP0;                                         \
    ENDS;                                                                      \
  } while (0)

__global__ __launch_bounds__(512, 2) void gemm8(
    const unsigned short* __restrict__ A,    // [NTOK, D_IN] bf16
    const unsigned short* __restrict__ B,    // [D_OUT, D_IN] bf16 (W cast)
    const float* __restrict__ bias,
    const unsigned short* __restrict__ y1b,  // [NTOK, 32] bf16 (cols 16-31 = 0)
    const unsigned short* __restrict__ Lb,   // [D_OUT, 32] bf16 (cols 16-31 = 0)
    float* __restrict__ C) {                 // [NTOK, D_OUT] fp32
  __shared__ __align__(16) unsigned char smem[131072];

  const int tid = threadIdx.x;
  const int lane = tid & 63;
  const int w  = tid >> 6;
  const int wm = (w >> 2) * 128;
  const int wn = (w & 3) * 64;
  const int fr  = lane & 15;
  const int fkb = (lane >> 4) * 16;
  const int fke = (lane >> 4) * 8;

  // hoisted swizzle constants (addr = base + frag*2048 + kx)
  const int kx0 = fkb ^ ((fr & 7) << 4);
  const int kx1 = kx0 ^ 64;
  const int baseA = (wm + fr) * 128;
  const int baseB = 32768 + (wn + fr) * 128;

  // T1: bijective XCD swizzle (512 WGs, 512%8==0)
  const int bid  = blockIdx.x;
  const int swzb = (bid & 7) * 64 + (bid >> 3);
  const int m0 = (swzb & 31) * BM;
  const int n0 = (swzb >> 5) * BN;

  // T2 staging: linear LDS dest, source permuted by the same involution.
  const int tsrc = tid ^ ((tid >> 3) & 7);
  const int sr_  = tsrc >> 3;
  const int sc8  = (tsrc & 7) * 8;
  const unsigned short* pa = A + (size_t)(m0 + sr_) * D_IN + sc8;
  const unsigned short* pb = B + (size_t)(n0 + sr_) * D_IN + sc8;

  floatx4 acc[8][4] = {};

  // prologue: T0 fully (8 loads) + T1.B (4 loads); vmcnt(4) => T0 landed.
  STG(pa, 0, 0, 0, 0);       STG(pa, 1, 0, 0, 0);
  STG(pb, 0, 0, 0, 32768);   STG(pb, 1, 0, 0, 32768);
  STG(pb, 0, 1, 65536, 32768); STG(pb, 1, 1, 65536, 32768);
  ENDS4;

  for (int t2 = 0; t2 < 31; ++t2) {
    const int T = t2 * 2;
    KTILE(0,     65536, T,     true, true, ENDS4);
    KTILE(65536, 0,     T + 1, true, true, ENDS4);
  }
  KTILE(0,     65536, 62, true,  false, ENDS0);
  KTILE(65536, 0,     63, false, false, ENDSN);

  // peeled rank-16 LoRA K-step (y1b/Lb are L2-hot, zero-padded to K=32)
  {
    short8 lbv[4];
#pragma unroll
    for (int j = 0; j < 4; ++j)
      lbv[j] = *(const short8*)(Lb + (size_t)(n0 + wn + j * 16 + fr) * 32 + fke);
#pragma unroll
    for (int i = 0; i < 8; ++i) {
      const short8 yav = *(const short8*)(y1b + (size_t)(m0 + wm + i * 16 + fr) * 32 + fke);
#pragma unroll
      for (int j = 0; j < 4; ++j)
        acc[i][j] = __builtin_amdgcn_mfma_f32_16x16x32_bf16(yav, lbv[j],
                                                            acc[i][j], 0, 0, 0);
    }
  }

  // epilogue: C/D layout col=lane&15, row=(lane>>4)*4+reg
  const int q4 = (lane >> 4) * 4;
#pragma unroll
  for (int j = 0; j < 4; ++j) {
    const int col = n0 + wn + j * 16 + fr;
    const float bs = bias[col];
#pragma unroll
    for (int i = 0; i < 8; ++i) {
      const size_t row = (size_t)(m0 + wm + i * 16 + q4);
      const floatx4 v = acc[i][j];
#pragma unroll
      for (int r = 0; r < 4; ++r)
        C[(row + r) * D_OUT + col] = v[r] + bs;
    }
  }
}

// ---------------------------------------------------------------------------
extern "C" void kernel_launch(void* const* d_in, const int* in_sizes, int n_in,
                              void* d_out, int out_size, void* d_ws, size_t ws_size,
                              hipStream_t stream) {
  const float* x    = (const float*)d_in[0];
  const float* W    = (const float*)d_in[1];
  const float* bias = (const float*)d_in[2];
  const float* L    = (const float*)d_in[3];
  const float* R    = (const float*)d_in[4];
  float* out = (float*)d_out;

  const size_t n_xb  = (size_t)NTOK * D_IN;
  const size_t n_wb  = (size_t)D_OUT * D_IN;
  const size_t n_y1b = (size_t)NTOK * 32;
  const size_t n_rb  = (size_t)LORA_DIM * D_IN;
  const size_t n_lb  = (size_t)D_OUT * 32;
  const size_t need = (n_xb + n_wb + n_y1b + n_rb + n_lb) * sizeof(unsigned short);
  if (ws_size < need) return;

  unsigned short* xb  = (unsigned short*)d_ws;
  unsigned short* wb  = xb + n_xb;
  unsigned short* y1b = wb + n_wb;
  unsigned short* Rb  = y1b + n_y1b;
  unsigned short* Lb  = Rb + n_rb;

  cvt<<<2048, 256, 0, stream>>>(x, W, L, R, xb, wb, Rb, Lb);
  lora_xr<<<512, 256, 0, stream>>>(xb, Rb, y1b);
  gemm8<<<dim3((NTOK / BM) * (D_OUT / BN)), 512, 0, stream>>>(xb, wb, bias, y1b, Lb, out);
}